// Round 2
// baseline (423.769 us; speedup 1.0000x reference)
//
#include <hip/hip_runtime.h>
#include <hip/hip_bf16.h>

// out[n] = sum_k U[k] * relu( x1[n,:] . M[k,:] + c[k] )
//   M[k,d] = V[k,d] + sum_e W[k,d,e]*x2[e]        (K=16, D=128)
//   c[k]   = sum_e V[k,128+e]*x2[e] + b[k]

#define D 128
#define KK 16

// ---------- prep: one wave per output element (2048 M + 16 c = 2064 waves) ----------
__global__ __launch_bounds__(256) void ntn_prep(const float* __restrict__ x2,
                                                const float* __restrict__ V,
                                                const float* __restrict__ W,
                                                const float* __restrict__ b,
                                                float* __restrict__ M,
                                                float* __restrict__ c) {
    const int gtid = blockIdx.x * 256 + threadIdx.x;
    const int wave = gtid >> 6;
    const int lane = gtid & 63;
    if (wave >= KK * D + KK) return;

    float p;
    if (wave < KK * D) {
        const int k = wave >> 7, d = wave & (D - 1);
        const float* Wr = W + ((size_t)(k * D + d)) * D;
        p = Wr[lane] * x2[lane] + Wr[lane + 64] * x2[lane + 64];
    } else {
        const int k = wave - KK * D;
        const float* Vr = V + (size_t)k * 2 * D + D;   // second half of V row
        p = Vr[lane] * x2[lane] + Vr[lane + 64] * x2[lane + 64];
    }
#pragma unroll
    for (int m = 32; m; m >>= 1) p += __shfl_xor(p, m);

    if (lane == 0) {
        if (wave < KK * D) {
            const int k = wave >> 7, d = wave & (D - 1);
            M[wave] = V[(size_t)k * 2 * D + d] + p;
        } else {
            const int k = wave - KK * D;
            c[k] = p + b[k];
        }
    }
}

// ---------- main: wave handles 8 rows/iter; lane = (row r = l>>3, colgroup g = l&7) ----------
// x: 4 float4 per lane, wave covers contiguous 4KB (addr = base + 64*l .. +63)
// M in LDS, swizzled [k][q][g][4] so ds_read_b128 (fixed k,q; varying g) is conflict-free.
__global__ __launch_bounds__(256) void ntn_main(const float* __restrict__ x1,
                                                const float* __restrict__ Mg,
                                                const float* __restrict__ c,
                                                const float* __restrict__ U,
                                                float* __restrict__ out,
                                                int N) {
    __shared__ float Ml[KK * D];   // 8 KB, swizzled

    const int t = threadIdx.x;
#pragma unroll
    for (int i = 0; i < 8; ++i) {
        int idx = i * 256 + t;                    // 0..2047
        int k = idx >> 7, col = idx & (D - 1);
        int g = col >> 4, q = (col >> 2) & 3, m = col & 3;
        Ml[k * D + q * 32 + g * 4 + m] = Mg[idx];
    }
    __syncthreads();

    // c/U are wave-uniform loads -> scalarized, hoisted out of the row loop
    float cu_c[KK], cu_u[KK];
#pragma unroll
    for (int k = 0; k < KK; ++k) { cu_c[k] = c[k]; cu_u[k] = U[k]; }

    const int w = t >> 6;          // wave in block
    const int l = t & 63;          // lane
    const int g = l & 7;           // column group (16 cols)
    const int r = l >> 3;          // row within 8-row group
    const int row0 = blockIdx.x * 256 + w * 64;

    for (int it = 0; it < 8; ++it) {
        const int row = row0 + it * 8 + r;

        float4 xa, xb, xc, xd;
        if (row < N) {
            const float4* xp = (const float4*)(x1 + (size_t)row * D + g * 16);
            xa = xp[0]; xb = xp[1]; xc = xp[2]; xd = xp[3];
        } else {
            xa = xb = xc = xd = make_float4(0.f, 0.f, 0.f, 0.f);
        }

        float acc[KK];
#pragma unroll
        for (int k = 0; k < KK; ++k) {
            const float4* mrow = (const float4*)(Ml + k * D) + g;  // [k][q][g][4]
            float4 m0 = mrow[0];     // q=0
            float4 m1 = mrow[8];     // q=1 (+32 floats)
            float4 m2 = mrow[16];    // q=2
            float4 m3 = mrow[24];    // q=3
            float a = 0.f;
            a = fmaf(xa.x, m0.x, a); a = fmaf(xa.y, m0.y, a);
            a = fmaf(xa.z, m0.z, a); a = fmaf(xa.w, m0.w, a);
            a = fmaf(xb.x, m1.x, a); a = fmaf(xb.y, m1.y, a);
            a = fmaf(xb.z, m1.z, a); a = fmaf(xb.w, m1.w, a);
            a = fmaf(xc.x, m2.x, a); a = fmaf(xc.y, m2.y, a);
            a = fmaf(xc.z, m2.z, a); a = fmaf(xc.w, m2.w, a);
            a = fmaf(xd.x, m3.x, a); a = fmaf(xd.y, m3.y, a);
            a = fmaf(xd.z, m3.z, a); a = fmaf(xd.w, m3.w, a);
            acc[k] = a;
        }

        // reduce over the 8 lanes (g) sharing this row
#pragma unroll
        for (int k = 0; k < KK; ++k) {
            acc[k] += __shfl_xor(acc[k], 1);
            acc[k] += __shfl_xor(acc[k], 2);
            acc[k] += __shfl_xor(acc[k], 4);
        }

        float s = 0.f;
#pragma unroll
        for (int k = 0; k < KK; ++k)
            s = fmaf(cu_u[k], fmaxf(acc[k] + cu_c[k], 0.f), s);

        if (g == 0 && row < N) out[row] = s;
    }
}

extern "C" void kernel_launch(void* const* d_in, const int* in_sizes, int n_in,
                              void* d_out, int out_size, void* d_ws, size_t ws_size,
                              hipStream_t stream) {
    const float* x1 = (const float*)d_in[0];
    const float* x2 = (const float*)d_in[1];
    const float* V  = (const float*)d_in[2];
    const float* W  = (const float*)d_in[3];
    const float* b  = (const float*)d_in[4];
    const float* U  = (const float*)d_in[5];
    float* out = (float*)d_out;

    float* M = (float*)d_ws;          // K*D floats
    float* c = M + KK * D;            // K floats

    const int N = in_sizes[0] / D;    // 500000

    // 2064 waves for prep -> 516 blocks of 256 threads
    ntn_prep<<<516, 256, 0, stream>>>(x2, V, W, b, M, c);

    // main: each block covers 256 rows
    int grid = (N + 255) / 256;
    ntn_main<<<grid, 256, 0, stream>>>(x1, M, c, U, out, N);
}

// Round 3
// 353.873 us; speedup vs baseline: 1.1975x; 1.1975x over previous
//
#include <hip/hip_runtime.h>
#include <hip/hip_bf16.h>

// out[n] = sum_k U[k] * relu( x1[n,:] . M[k,:] + c[k] )
//   M[k,d] = V[k,d] + sum_e W[k,d,e]*x2[e]        (K=16, D=128)
//   c[k]   = sum_e V[k,128+e]*x2[e] + b[k]
//
// Main kernel: C(16rows x 16k) tiles via mfma_f32_16x16x32_bf16, split-precision
// (x = xh+xl, M = Mh+Ml bf16; dot = xh*Mh + xh*Ml + xl*Mh). M fragments live in
// VGPRs for the whole kernel -> no LDS at all, pure streaming of x1.

#define D 128
#define KK 16

typedef __attribute__((ext_vector_type(8))) short bf16x8;
typedef __attribute__((ext_vector_type(4))) float f32x4;

__device__ __forceinline__ unsigned short f2bf(float f) {   // RNE
    unsigned u = __float_as_uint(f);
    unsigned t = u + 0x7fffu + ((u >> 16) & 1u);
    return (unsigned short)(t >> 16);
}
__device__ __forceinline__ float bf2f(unsigned short s) {
    return __uint_as_float(((unsigned)s) << 16);
}

// ---------- prep: wave per M element (2048) + wave per c element (16) ----------
// Writes Mh/Ml in B-fragment order: bh[kb*512 + lane*8 + j] = bf16(M[n][kb*32+kk])
// where lane = n | ((kk>>3)<<4), j = kk&7  (B[k][n]: n=lane&15, k=(lane>>4)*8+j).
__global__ __launch_bounds__(256) void ntn_prep(const float* __restrict__ x2,
                                                const float* __restrict__ V,
                                                const float* __restrict__ W,
                                                const float* __restrict__ b,
                                                unsigned short* __restrict__ bh,
                                                unsigned short* __restrict__ bl,
                                                float* __restrict__ c) {
    const int gtid = blockIdx.x * 256 + threadIdx.x;
    const int wave = gtid >> 6;
    const int lane = gtid & 63;
    if (wave >= KK * D + KK) return;

    float p;
    if (wave < KK * D) {
        const int k = wave >> 7, d = wave & (D - 1);
        const float* Wr = W + ((size_t)(k * D + d)) * D;
        p = Wr[lane] * x2[lane] + Wr[lane + 64] * x2[lane + 64];
    } else {
        const int k = wave - KK * D;
        const float* Vr = V + (size_t)k * 2 * D + D;
        p = Vr[lane] * x2[lane] + Vr[lane + 64] * x2[lane + 64];
    }
#pragma unroll
    for (int m = 32; m; m >>= 1) p += __shfl_xor(p, m);

    if (lane == 0) {
        if (wave < KK * D) {
            const int k = wave >> 7, d = wave & (D - 1);
            float Mv = V[(size_t)k * 2 * D + d] + p;
            unsigned short hb = f2bf(Mv);
            unsigned short lb = f2bf(Mv - bf2f(hb));
            const int kb = d >> 5, kk = d & 31;
            const int fl = k | ((kk >> 3) << 4);
            const int idx = kb * 512 + fl * 8 + (kk & 7);
            bh[idx] = hb;
            bl[idx] = lb;
        } else {
            const int k = wave - KK * D;
            c[k] = p + b[k];
        }
    }
}

// ---------- main: one wave -> 16-row tiles; M frags register-resident ----------
__global__ __launch_bounds__(256, 4) void ntn_main(const float* __restrict__ x1,
                                                   const unsigned short* __restrict__ bhp,
                                                   const unsigned short* __restrict__ blp,
                                                   const float* __restrict__ cp,
                                                   const float* __restrict__ Up,
                                                   float* __restrict__ out,
                                                   int NT, int TW) {
    const int t = threadIdx.x;
    const int l = t & 63;
    const int gw = blockIdx.x * 4 + (t >> 6);

    // B fragments (loaded once, reused for every tile)
    bf16x8 Bh[4], Bl[4];
#pragma unroll
    for (int kb = 0; kb < 4; ++kb) {
        Bh[kb] = *(const bf16x8*)(bhp + kb * 512 + l * 8);
        Bl[kb] = *(const bf16x8*)(blp + kb * 512 + l * 8);
    }
    const int m = l & 15;     // A row within tile / C col (k-index) owner
    const int q = l >> 4;     // k-quad: A k-range q*8..q*8+7 ; C rows q*4..q*4+3
    const float cl = cp[m];
    const float ul = Up[m];

    int i = gw;
    if (i >= NT) return;

    float4 cur[8];
    {
        const float4* p = (const float4*)(x1 + ((size_t)i * 16 + m) * D + q * 8);
#pragma unroll
        for (int kb = 0; kb < 4; ++kb) { cur[2 * kb] = p[kb * 8]; cur[2 * kb + 1] = p[kb * 8 + 1]; }
    }

    while (true) {
        const int nx = i + TW;
        const bool has = nx < NT;
        float4 nb[8];
        if (has) {
            const float4* p = (const float4*)(x1 + ((size_t)nx * 16 + m) * D + q * 8);
#pragma unroll
            for (int kb = 0; kb < 4; ++kb) { nb[2 * kb] = p[kb * 8]; nb[2 * kb + 1] = p[kb * 8 + 1]; }
        }

        f32x4 accA = {0.f, 0.f, 0.f, 0.f};
        f32x4 accB = {0.f, 0.f, 0.f, 0.f};
#pragma unroll
        for (int kb = 0; kb < 4; ++kb) {
            const float f[8] = {cur[2 * kb].x,     cur[2 * kb].y,     cur[2 * kb].z,     cur[2 * kb].w,
                                cur[2 * kb + 1].x, cur[2 * kb + 1].y, cur[2 * kb + 1].z, cur[2 * kb + 1].w};
            bf16x8 ah, al;
#pragma unroll
            for (int j = 0; j < 8; ++j) {
                unsigned short hb = f2bf(f[j]);
                ah[j] = (short)hb;
                al[j] = (short)f2bf(f[j] - bf2f(hb));
            }
            accA = __builtin_amdgcn_mfma_f32_16x16x32_bf16(ah, Bh[kb], accA, 0, 0, 0);
            accB = __builtin_amdgcn_mfma_f32_16x16x32_bf16(ah, Bl[kb], accB, 0, 0, 0);
            accA = __builtin_amdgcn_mfma_f32_16x16x32_bf16(al, Bh[kb], accA, 0, 0, 0);
        }

        // epilogue: relu + U, reduce over k (lanes sharing q), coalesced float4 store
        float4 v;
        {
            float vv[4];
#pragma unroll
            for (int r = 0; r < 4; ++r) {
                float s = accA[r] + accB[r] + cl;
                vv[r] = ul * fmaxf(s, 0.f);
                vv[r] += __shfl_xor(vv[r], 1);
                vv[r] += __shfl_xor(vv[r], 2);
                vv[r] += __shfl_xor(vv[r], 4);
                vv[r] += __shfl_xor(vv[r], 8);
            }
            v = make_float4(vv[0], vv[1], vv[2], vv[3]);
        }
        if (m == 0) *(float4*)(out + (size_t)i * 16 + q * 4) = v;

        if (!has) break;
#pragma unroll
        for (int j = 0; j < 8; ++j) cur[j] = nb[j];
        i = nx;
    }
}

extern "C" void kernel_launch(void* const* d_in, const int* in_sizes, int n_in,
                              void* d_out, int out_size, void* d_ws, size_t ws_size,
                              hipStream_t stream) {
    const float* x1 = (const float*)d_in[0];
    const float* x2 = (const float*)d_in[1];
    const float* V  = (const float*)d_in[2];
    const float* W  = (const float*)d_in[3];
    const float* b  = (const float*)d_in[4];
    const float* U  = (const float*)d_in[5];
    float* out = (float*)d_out;

    unsigned short* bh = (unsigned short*)d_ws;          // 2048 bf16
    unsigned short* bl = bh + KK * D;                    // 2048 bf16
    float* c = (float*)(bl + KK * D);                    // 16 f32

    const int N = in_sizes[0] / D;    // 500000
    const int NT = N >> 4;            // 31250 tiles of 16 rows (exact)

    ntn_prep<<<516, 256, 0, stream>>>(x2, V, W, b, bh, bl, c);

    const int blocks = 1024;          // 4 waves each -> TW = 4096 wave-strides
    ntn_main<<<blocks, 256, 0, stream>>>(x1, bh, bl, c, U, out, NT, blocks * 4);
}

// Round 4
// 349.279 us; speedup vs baseline: 1.2133x; 1.0132x over previous
//
#include <hip/hip_runtime.h>
#include <hip/hip_bf16.h>

// out[n] = sum_k U[k] * relu( x1[n,:] . M[k,:] + c[k] )
//   M[k,d] = V[k,d] + sum_e W[k,d,e]*x2[e]        (K=16, D=128)
//   c[k]   = sum_e V[k,128+e]*x2[e] + b[k]
//
// Main kernel: C(16rows x 16k) tiles via mfma_f32_16x16x32_bf16.
// Precision scheme: x -> bf16 (RNE, single), M -> bf16 split (Mh + Ml);
// dot = x*Mh + x*Ml. M fragments (Bh, Bl) are register-resident for the
// whole kernel; no LDS; x1 is streamed once with 1-tile register prefetch.
// Register budget ~110 VGPR -> fits __launch_bounds__(256,4) without spill
// (R3's 3-MFMA variant needed ~135 and spilled -> ~105us).

#define D 128
#define KK 16

typedef __attribute__((ext_vector_type(8))) short bf16x8;
typedef __attribute__((ext_vector_type(4))) float f32x4;

__device__ __forceinline__ unsigned short f2bf(float f) {   // RNE
    unsigned u = __float_as_uint(f);
    unsigned t = u + 0x7fffu + ((u >> 16) & 1u);
    return (unsigned short)(t >> 16);
}
__device__ __forceinline__ float bf2f(unsigned short s) {
    return __uint_as_float(((unsigned)s) << 16);
}

// ---------- prep: wave per M element (2048) + wave per c element (16) ----------
// Writes Mh/Ml in B-fragment order: b[kb*512 + lane*8 + j] = bf16(M[n][kb*32+kk])
// where lane = n | ((kk>>3)<<4), j = kk&7  (B[k][n]: n=lane&15, k=(lane>>4)*8+j).
__global__ __launch_bounds__(256) void ntn_prep(const float* __restrict__ x2,
                                                const float* __restrict__ V,
                                                const float* __restrict__ W,
                                                const float* __restrict__ b,
                                                unsigned short* __restrict__ bh,
                                                unsigned short* __restrict__ bl,
                                                float* __restrict__ c) {
    const int gtid = blockIdx.x * 256 + threadIdx.x;
    const int wave = gtid >> 6;
    const int lane = gtid & 63;
    if (wave >= KK * D + KK) return;

    float p;
    if (wave < KK * D) {
        const int k = wave >> 7, d = wave & (D - 1);
        const float* Wr = W + ((size_t)(k * D + d)) * D;
        p = Wr[lane] * x2[lane] + Wr[lane + 64] * x2[lane + 64];
    } else {
        const int k = wave - KK * D;
        const float* Vr = V + (size_t)k * 2 * D + D;
        p = Vr[lane] * x2[lane] + Vr[lane + 64] * x2[lane + 64];
    }
#pragma unroll
    for (int m = 32; m; m >>= 1) p += __shfl_xor(p, m);

    if (lane == 0) {
        if (wave < KK * D) {
            const int k = wave >> 7, d = wave & (D - 1);
            float Mv = V[(size_t)k * 2 * D + d] + p;
            unsigned short hb = f2bf(Mv);
            unsigned short lb = f2bf(Mv - bf2f(hb));
            const int kb = d >> 5, kk = d & 31;
            const int fl = k | ((kk >> 3) << 4);
            const int idx = kb * 512 + fl * 8 + (kk & 7);
            bh[idx] = hb;
            bl[idx] = lb;
        } else {
            const int k = wave - KK * D;
            c[k] = p + b[k];
        }
    }
}

// ---------- main: one wave -> 16-row tiles; M frags register-resident ----------
__global__ __launch_bounds__(256, 4) void ntn_main(const float* __restrict__ x1,
                                                   const unsigned short* __restrict__ bhp,
                                                   const unsigned short* __restrict__ blp,
                                                   const float* __restrict__ cp,
                                                   const float* __restrict__ Up,
                                                   float* __restrict__ out,
                                                   int NT, int TW) {
    const int t = threadIdx.x;
    const int l = t & 63;
    const int gw = blockIdx.x * 4 + (t >> 6);

    // B fragments (loaded once, reused for every tile): 32 VGPR total
    bf16x8 Bh[4], Bl[4];
#pragma unroll
    for (int kb = 0; kb < 4; ++kb) {
        Bh[kb] = *(const bf16x8*)(bhp + kb * 512 + l * 8);
        Bl[kb] = *(const bf16x8*)(blp + kb * 512 + l * 8);
    }
    const int m = l & 15;     // A row within tile / C col (k) owner
    const int q = l >> 4;     // k-quad: A k-range q*8..q*8+7 ; C rows q*4..q*4+3
    const float cl = cp[m];
    const float ul = Up[m];

    int i = gw;
    if (i >= NT) return;

    float4 cur[8];
    {
        const float4* p = (const float4*)(x1 + ((size_t)i * 16 + m) * D + q * 8);
#pragma unroll
        for (int kb = 0; kb < 4; ++kb) { cur[2 * kb] = p[kb * 8]; cur[2 * kb + 1] = p[kb * 8 + 1]; }
    }

    while (true) {
        const int nx = i + TW;
        const bool has = nx < NT;
        float4 nb[8];
        if (has) {
            const float4* p = (const float4*)(x1 + ((size_t)nx * 16 + m) * D + q * 8);
#pragma unroll
            for (int kb = 0; kb < 4; ++kb) { nb[2 * kb] = p[kb * 8]; nb[2 * kb + 1] = p[kb * 8 + 1]; }
        }

        f32x4 accA = {0.f, 0.f, 0.f, 0.f};
        f32x4 accB = {0.f, 0.f, 0.f, 0.f};
#pragma unroll
        for (int kb = 0; kb < 4; ++kb) {
            const float f[8] = {cur[2 * kb].x,     cur[2 * kb].y,     cur[2 * kb].z,     cur[2 * kb].w,
                                cur[2 * kb + 1].x, cur[2 * kb + 1].y, cur[2 * kb + 1].z, cur[2 * kb + 1].w};
            bf16x8 ah;
#pragma unroll
            for (int j = 0; j < 8; ++j) ah[j] = (short)f2bf(f[j]);
            accA = __builtin_amdgcn_mfma_f32_16x16x32_bf16(ah, Bh[kb], accA, 0, 0, 0);
            accB = __builtin_amdgcn_mfma_f32_16x16x32_bf16(ah, Bl[kb], accB, 0, 0, 0);
        }

        // epilogue: relu + U, reduce over k (16 lanes sharing q), float4 store
        float4 v;
        {
            float vv[4];
#pragma unroll
            for (int r = 0; r < 4; ++r) {
                float s = accA[r] + accB[r] + cl;
                vv[r] = ul * fmaxf(s, 0.f);
                vv[r] += __shfl_xor(vv[r], 1);
                vv[r] += __shfl_xor(vv[r], 2);
                vv[r] += __shfl_xor(vv[r], 4);
                vv[r] += __shfl_xor(vv[r], 8);
            }
            v = make_float4(vv[0], vv[1], vv[2], vv[3]);
        }
        if (m == 0) *(float4*)(out + (size_t)i * 16 + q * 4) = v;

        if (!has) break;
#pragma unroll
        for (int j = 0; j < 8; ++j) cur[j] = nb[j];
        i = nx;
    }
}

extern "C" void kernel_launch(void* const* d_in, const int* in_sizes, int n_in,
                              void* d_out, int out_size, void* d_ws, size_t ws_size,
                              hipStream_t stream) {
    const float* x1 = (const float*)d_in[0];
    const float* x2 = (const float*)d_in[1];
    const float* V  = (const float*)d_in[2];
    const float* W  = (const float*)d_in[3];
    const float* b  = (const float*)d_in[4];
    const float* U  = (const float*)d_in[5];
    float* out = (float*)d_out;

    unsigned short* bh = (unsigned short*)d_ws;          // 2048 bf16
    unsigned short* bl = bh + KK * D;                    // 2048 bf16
    float* c = (float*)(bl + KK * D);                    // 16 f32

    const int N = in_sizes[0] / D;    // 500000
    const int NT = N >> 4;            // 31250 tiles of 16 rows (exact)

    ntn_prep<<<516, 256, 0, stream>>>(x2, V, W, b, bh, bl, c);

    // 1024 blocks x 4 waves = 4096 waves = exactly 16 waves/CU resident in one round
    const int blocks = 1024;
    ntn_main<<<blocks, 256, 0, stream>>>(x1, bh, bl, c, U, out, NT, blocks * 4);
}